// Round 11
// baseline (523.610 us; speedup 1.0000x reference)
//
#include <hip/hip_runtime.h>

typedef __bf16 bf16x8 __attribute__((ext_vector_type(8)));
typedef float f32x4 __attribute__((ext_vector_type(4)));
typedef int i32x4 __attribute__((ext_vector_type(4)));
typedef unsigned short u16;

#define IN_F 4096
#define OUT_F 4096
#define NTOK 4096
#define RANK 32

// LDS map (bytes)
#define D0A 0
#define D0B 16384
#define D1A 32768
#define D1B 49152
#define WSL 65536      /* wscale_t slab 64KB: [64][256] f32 */
#define ASL 131072     /* ascale slab 1KB */
#define LDS_TOT 132096

// round-to-nearest-even f32 -> bf16
__device__ __forceinline__ u16 f2bf(float f) {
  union { float f; unsigned u; } c; c.f = f;
  unsigned u = c.u;
  return (u16)((u + 0x7FFFu + ((u >> 16) & 1u)) >> 16);
}

__device__ __forceinline__ void gload_lds16(const void* g, void* l) {
  __builtin_amdgcn_global_load_lds((const __attribute__((address_space(1))) void*)g,
                                   (__attribute__((address_space(3))) void*)l,
                                   16, 0, 0);
}
__device__ __forceinline__ void gload_lds4(const void* g, void* l) {
  __builtin_amdgcn_global_load_lds((const __attribute__((address_space(1))) void*)g,
                                   (__attribute__((address_space(3))) void*)l,
                                   4, 0, 0);
}

// ---------------- prep: per-token amax -> ascale, int8 codes ----------------
__global__ __launch_bounds__(256) void prep_kernel(const float* __restrict__ x,
                                                   char* __restrict__ A8,
                                                   float* __restrict__ ascale) {
  int t = blockIdx.x;
  int tid = threadIdx.x;
  const float4* xr = (const float4*)(x + (size_t)t * IN_F);
  float4 v[4];
  float m = 0.f;
#pragma unroll
  for (int i = 0; i < 4; ++i) {
    v[i] = xr[tid + i * 256];
    m = fmaxf(m, fmaxf(fmaxf(fabsf(v[i].x), fabsf(v[i].y)),
                       fmaxf(fabsf(v[i].z), fabsf(v[i].w))));
  }
#pragma unroll
  for (int off = 32; off > 0; off >>= 1) m = fmaxf(m, __shfl_xor(m, off));
  __shared__ float wmax[4];
  if ((tid & 63) == 0) wmax[tid >> 6] = m;
  __syncthreads();
  m = fmaxf(fmaxf(wmax[0], wmax[1]), fmaxf(wmax[2], wmax[3]));
  float as = fmaxf(m, 1e-6f) / 7.f;
  float inv = 1.f / as;
  if (tid == 0) ascale[t] = as;
  char* Ar = A8 + (size_t)t * IN_F;
#pragma unroll
  for (int i = 0; i < 4; ++i) {
    float q0 = fminf(fmaxf(rintf(v[i].x * inv), -8.f), 7.f);
    float q1 = fminf(fmaxf(rintf(v[i].y * inv), -8.f), 7.f);
    float q2 = fminf(fmaxf(rintf(v[i].z * inv), -8.f), 7.f);
    float q3 = fminf(fmaxf(rintf(v[i].w * inv), -8.f), 7.f);
    char4 c;
    c.x = (char)(int)q0; c.y = (char)(int)q1; c.z = (char)(int)q2; c.w = (char)(int)q3;
    *(char4*)(Ar + (size_t)(tid + i * 256) * 4) = c;
  }
}

// ---------------- dequant: int4 codes -> int8 (no scaling), lu -> bf16 ----------------
__global__ __launch_bounds__(256) void dequant_kernel(const int* __restrict__ qw,
                                                      const float* __restrict__ lu,
                                                      char* __restrict__ B8,
                                                      u16* __restrict__ lub) {
  int o = blockIdx.x;
  int tid = threadIdx.x;
  const int4* qr = (const int4*)(qw + (size_t)o * IN_F);
  char* Br = B8 + (size_t)o * IN_F;
#pragma unroll
  for (int s = 0; s < 4; ++s) {
    int e = tid + s * 256;
    int4 q = qr[e];
    char4 c;
    c.x = (char)q.x; c.y = (char)q.y; c.z = (char)q.z; c.w = (char)q.w;
    *(char4*)(Br + (size_t)4 * e) = c;
  }
  if (tid < RANK) lub[(size_t)o * RANK + tid] = f2bf(lu[(size_t)o * RANK + tid]);
}

// ---------------- wtr: wscale[4096][64] -> wscale_t[64][4096] ----------------
__global__ __launch_bounds__(256) void wtr_kernel(const float* __restrict__ wscale,
                                                  float* __restrict__ wst) {
  int idx = blockIdx.x * 256 + threadIdx.x;   // 262144
  float v = wscale[idx];
  wst[(size_t)(idx & 63) * OUT_F + (idx >> 6)] = v;
}

// ---------------- lorad: tr = x @ ld^T, split-K=8 partials ----------------
__global__ __launch_bounds__(256) void lorad_kernel(const float* __restrict__ x,
                                                    const float* __restrict__ ld,
                                                    float* __restrict__ tr8) {
  __shared__ float Xs[128][68];
  __shared__ float Ls[32][68];
  int b = blockIdx.x;
  int t0 = (b >> 3) * 128;
  int kbase = (b & 7) * 512;
  int tid = threadIdx.x;
  int rb = tid & 7;
  int tb = tid >> 3;
  float acc[4][4];
#pragma unroll
  for (int i = 0; i < 4; ++i)
#pragma unroll
    for (int j = 0; j < 4; ++j) acc[i][j] = 0.f;

  for (int kc = 0; kc < 512; kc += 64) {
    int k0 = kbase + kc;
    __syncthreads();
#pragma unroll
    for (int s = 0; s < 8; ++s) {
      int e = tid + s * 256;
      int row = e >> 4, c4 = (e & 15) * 4;
      float4 vv = *(const float4*)(x + (size_t)(t0 + row) * IN_F + k0 + c4);
      *(float4*)&Xs[row][c4] = vv;
    }
#pragma unroll
    for (int s = 0; s < 2; ++s) {
      int e = tid + s * 256;
      int row = e >> 4, c4 = (e & 15) * 4;
      float4 vv = *(const float4*)(ld + (size_t)row * IN_F + k0 + c4);
      *(float4*)&Ls[row][c4] = vv;
    }
    __syncthreads();
    for (int k4 = 0; k4 < 64; k4 += 4) {
      float4 lv[4], xv[4];
#pragma unroll
      for (int r = 0; r < 4; ++r) lv[r] = *(float4*)&Ls[rb + r * 8][k4];
#pragma unroll
      for (int mm = 0; mm < 4; ++mm) xv[mm] = *(float4*)&Xs[tb + mm * 32][k4];
#pragma unroll
      for (int mm = 0; mm < 4; ++mm)
#pragma unroll
        for (int r = 0; r < 4; ++r)
          acc[mm][r] += xv[mm].x * lv[r].x + xv[mm].y * lv[r].y +
                        xv[mm].z * lv[r].z + xv[mm].w * lv[r].w;
    }
  }
  float* dst = tr8 + (size_t)(b & 7) * NTOK * RANK;
#pragma unroll
  for (int mm = 0; mm < 4; ++mm)
#pragma unroll
    for (int r = 0; r < 4; ++r)
      dst[(size_t)(t0 + tb + mm * 32) * RANK + rb + r * 8] = acc[mm][r];
}

// ---------------- trwrite: sum partials -> tr bf16 (no ascale) ----------------
__global__ __launch_bounds__(256) void trwrite_kernel(const float* __restrict__ tr8,
                                                      u16* __restrict__ trb) {
  int idx = blockIdx.x * 256 + threadIdx.x;
  float s = 0.f;
#pragma unroll
  for (int k = 0; k < 8; ++k) s += tr8[(size_t)k * NTOK * RANK + idx];
  trb[idx] = f2bf(s);
}

// ---------------- main GEMM: 256x256, i8 16x16x64, per-group wscale rescale ----------------
// K=4096 = 64 tiles of 64 (one quant group per tile, per MFMA). 2 tiles/iter,
// 32 iters, no tail. dbufs 32KB each (A 16K + B 16K), rows 64B linear (bank-
// balanced: 8 lanes/bank-quad = inherent b128 serialization, no swizzle).
// Rescale: iacc = mfma_i8(a,b,0) (exact int); facc[mn] += wscale[col,g]*cvt(iacc).
// Stage slots (r8 skeleton, 1-load units):
//   P1: Ad1.H1(2u+1) | P3: Bd0.H0+H1(2u+2) | P4: Ad0.H0+H1(2u+2), vmcnt(4)
//   P7: Bd1.H0(2u+3) | P8: Bd1.H1+Ad1.H0(2u+3), vmcnt(3)
// Steady ledger (per-wave): P4 vmcnt(4) forces exactly {P7',P8',P1} -> dbuf1
// fully staged (BOTH A halves, BOTH B halves) before ANY dbuf1 read (P4-slot..).
// P8 vmcnt(3) forces {P3,P4} -> dbuf0 complete before P8-slot/P1' reads.
// Every forced load >=3 phases old -> no HBM-latency stalls. Guards at u=31
// (tiles 64/65 don't exist): skip P3/P4/P7/P8 stages, P4 uses vmcnt(0).
// Epilogue: facc *= ascale[row]; facc = mfma_bf16(tr,lu,facc) ONE K=32 chunk
// (RANK=32 == MFMA K; r10's kk<2 loop double-counted K and over-read rows ->
// int8 bytes parsed as bf16 NaN -- fixed); +bias.

#define PH_SYNC() do { __builtin_amdgcn_sched_barrier(0); \
                       asm volatile("s_barrier" ::: "memory"); \
                       asm volatile("s_waitcnt lgkmcnt(0)" ::: "memory"); \
                       __builtin_amdgcn_sched_barrier(0); } while (0)
#define PH_END() do { __builtin_amdgcn_sched_barrier(0); \
                      asm volatile("s_barrier" ::: "memory"); } while (0)
#define SB() __builtin_amdgcn_sched_barrier(0)

// stage one 128-row half (8KB) of A or B for K-tile at byte offset kb
#define STG_A(dst, H, kb) gload_lds16(ag + (size_t)(H) * (128 * 4096) + (kb), \
                                      smem + (dst) + (H) * 8192 + tid * 16)
#define STG_B(dst, H, kb) gload_lds16(bg + (size_t)(H) * (128 * 4096) + (kb), \
                                      smem + (dst) + (H) * 8192 + tid * 16)

// A-frag: 4 m-blocks, one b128 each (16 K-bytes): row = wr*128 + h*64 + m*16 + l15
#define READ_A8(dst, dbase, h) \
  _Pragma("unroll") for (int m2_ = 0; m2_ < 4; ++m2_) \
    dst[m2_] = *(const i32x4*)(smem + (dbase) + (h) * 4096 + m2_ * 1024 + aoff8);

// B-frag: 2 n-blocks starting at nq: row = wc*64 + n*16 + l15
#define READ_B8(dst, dbase, nq) \
  _Pragma("unroll") for (int j_ = 0; j_ < 2; ++j_) \
    dst[j_] = *(const i32x4*)(smem + (dbase) + 16384 + ((nq) + j_) * 1024 + boff8);

// quadrant: 4 m x 2 n, one K=64 MFMA each + per-group rescale
#define MFMAQ8(aS, bU, mb, nq, w0, w1) do { \
  __builtin_amdgcn_s_setprio(1); \
  _Pragma("unroll") for (int m2_ = 0; m2_ < 4; ++m2_) { \
    i32x4 ia0 = __builtin_amdgcn_mfma_i32_16x16x64_i8(aS[0 + m2_], bU[0], zero4, 0, 0, 0); \
    i32x4 ia1 = __builtin_amdgcn_mfma_i32_16x16x64_i8(aS[0 + m2_], bU[1], zero4, 0, 0, 0); \
    _Pragma("unroll") for (int e_ = 0; e_ < 4; ++e_) { \
      facc[(mb) + m2_][(nq)][e_]     += (w0) * (float)ia0[e_]; \
      facc[(mb) + m2_][(nq) + 1][e_] += (w1) * (float)ia1[e_]; \
    } \
  } \
  __builtin_amdgcn_s_setprio(0); } while (0)

__global__ __launch_bounds__(512, 2) void gemm_kernel(const char* __restrict__ A8,
                                                      const char* __restrict__ B8,
                                                      const float* __restrict__ wst,
                                                      const float* __restrict__ ascale,
                                                      const u16* __restrict__ trb,
                                                      const u16* __restrict__ lub,
                                                      const float* __restrict__ bias,
                                                      float* __restrict__ out) {
  __shared__ __align__(16) char smem[LDS_TOT];
  int b = blockIdx.x;
  int swz = (b & 7) * 32 + (b >> 3);     // 256 blocks, 8 XCDs -> bijective
  int by = swz >> 4, bx = swz & 15;
  int tm = by * 256, tn = bx * 256;
  int tid = threadIdx.x;
  int lane = tid & 63, wid = tid >> 6;
  int wr = wid >> 2, wc = wid & 3;       // 2x4 wave grid; wave owns 128x64 of C
  int l15 = lane & 15, l4 = lane >> 4;
  int aoff8 = wr * 8192 + l15 * 64 + l4 * 16;
  int boff8 = wc * 4096 + l15 * 64 + l4 * 16;
  int wcol = WSL + (wc * 64 + l15) * 4;  // + g*1024 + nblock*64

  // staging bases: thread covers row (tid>>2), chunk (tid&3)*16 within 64B rows
  const char* ag = A8 + (size_t)(tm + (tid >> 2)) * 4096 + (tid & 3) * 16;
  const char* bg = B8 + (size_t)(tn + (tid >> 2)) * 4096 + (tid & 3) * 16;

  const i32x4 zero4 = {0, 0, 0, 0};
  f32x4 facc[8][4];
#pragma unroll
  for (int i = 0; i < 8; ++i)
#pragma unroll
    for (int j = 0; j < 4; ++j) facc[i][j] = (f32x4){0.f, 0.f, 0.f, 0.f};

  // prologue: wscale slab (8), ascale (1, waves 0-3), tile0 full (4), tile1 {B.H0,B.H1,A.H0} (3)
#pragma unroll
  for (int h = 0; h < 8; ++h)
    gload_lds16(wst + (size_t)(h * 8 + (tid >> 6)) * OUT_F + tn + (tid & 63) * 4,
                smem + WSL + h * 8192 + tid * 16);
  if (tid < 256)
    gload_lds4(ascale + tm + tid, smem + ASL + tid * 4);
  STG_A(D0A, 0, 0);  STG_A(D0A, 1, 0);
  STG_B(D0B, 0, 0);  STG_B(D0B, 1, 0);
  STG_B(D1B, 0, 64); STG_B(D1B, 1, 64);
  STG_A(D1A, 0, 64);
  asm volatile("s_waitcnt vmcnt(3)" ::: "memory");  // wscale/ascale/tile0 landed
  PH_END();

  i32x4 aS0[4], aS1[4], bU0[2], bU1[2];
  READ_A8(aS0, D0A, 0);   // A(T0) h0; drained by P1's lgkm0

  for (int u = 0; u < 32; ++u) {
    int kb0 = u * 128;            // T0 = 2u at byte kb0; T1 at +64; T2 +128; T3 +192
    bool lastu = (u == 31);
    float w0, w1, w2, w3;

    // ---- P1: stage Ad1.H1(2u+1); pre B(T0)n01 | slot B(T0)n23 | Q(A0,B01) ----
    STG_A(D1A, 1, kb0 + 64);
    READ_B8(bU0, D0A, 0);
    PH_SYNC();
    w0 = *(const float*)(smem + wcol + (2 * u) * 1024);
    w1 = *(const float*)(smem + wcol + (2 * u) * 1024 + 64);
    READ_B8(bU1, D0A, 2);
    SB();
    MFMAQ8(aS0, bU0, 0, 0, w0, w1);

    // ---- P2: slot A(T0)h1 | Q(A0,B23) ----
    PH_SYNC();
    w2 = *(const float*)(smem + wcol + (2 * u) * 1024 + 128);
    w3 = *(const float*)(smem + wcol + (2 * u) * 1024 + 192);
    READ_A8(aS1, D0A, 1);
    SB();
    MFMAQ8(aS0, bU1, 0, 2, w2, w3);
    PH_END();

    // ---- P3: stage Bd0 both halves (2u+2) | Q(A1,B23) ----
    if (!lastu) { STG_B(D0B, 0, kb0 + 128); STG_B(D0B, 1, kb0 + 128); }
    PH_SYNC();
    MFMAQ8(aS1, bU1, 4, 2, w2, w3);
    PH_END();

    // ---- P4: stage Ad0 both halves (2u+2); counted vmcnt | slot A(T1)h0 | Q(A1,B01) ----
    if (!lastu) {
      STG_A(D0A, 0, kb0 + 128); STG_A(D0A, 1, kb0 + 128);
      asm volatile("s_waitcnt vmcnt(4)" ::: "memory");  // forces P7',P8',P1 -> dbuf1 ready
    } else {
      asm volatile("s_waitcnt vmcnt(0)" ::: "memory");
    }
    PH_SYNC();
    READ_A8(aS0, D1A, 0);
    SB();
    MFMAQ8(aS1, bU0, 4, 0, w0, w1);

    // ---- P5: pre B(T1)n01 | slot B(T1)n23 | Q(A0,B01) ----
    READ_B8(bU0, D1A, 0);
    PH_SYNC();
    w0 = *(const float*)(smem + wcol + (2 * u + 1) * 1024);
    w1 = *(const float*)(smem + wcol + (2 * u + 1) * 1024 + 64);
    READ_B8(bU1, D1A, 2);
    SB();
    MFMAQ8(aS0, bU0, 0, 0, w0, w1);

    // ---- P6: slot A(T1)h1 | Q(A0,B23) ----
    PH_SYNC();
    w2 = *(const float*)(smem + wcol + (2 * u + 1) * 1024 + 128);
    w3 = *(const float*)(smem + wcol + (2 * u + 1) * 1024 + 192);
    READ_A8(aS1, D1A, 1);
    SB();
    MFMAQ8(aS0, bU1, 0, 2, w2, w3);
    PH_END();

    // ---- P7: stage Bd1.H0 (2u+3) | Q(A1,B23) ----
    if (!lastu) STG_B(D1B, 0, kb0 + 192);
    PH_SYNC();
    MFMAQ8(aS1, bU1, 4, 2, w2, w3);
    PH_END();

    // ---- P8: stage Bd1.H1 + Ad1.H0 (2u+3); counted vmcnt | slot A(T0')h0 | Q(A1,B01) ----
    if (!lastu) {
      STG_B(D1B, 1, kb0 + 192);
      STG_A(D1A, 0, kb0 + 192);
      asm volatile("s_waitcnt vmcnt(3)" ::: "memory");  // forces P3,P4 -> dbuf0 ready
    }
    PH_SYNC();
    if (!lastu) { READ_A8(aS0, D0A, 0); }
    SB();
    MFMAQ8(aS1, bU0, 4, 0, w0, w1);
    PH_END();
  }

  // ---- epilogue: stage tr/lu into dbuf space ----
  {
    const char* trg = (const char*)trb + (size_t)(tm + (tid >> 2)) * 64 + (tid & 3) * 16;
    gload_lds16(trg, smem + tid * 16);
    gload_lds16(trg + (size_t)128 * 64, smem + 8192 + tid * 16);
    const char* lug = (const char*)lub + (size_t)(tn + (tid >> 2)) * 64 + (tid & 3) * 16;
    gload_lds16(lug, smem + 16384 + tid * 16);
    gload_lds16(lug + (size_t)128 * 64, smem + 16384 + 8192 + tid * 16);
  }
  asm volatile("s_waitcnt vmcnt(0)" ::: "memory");
  asm volatile("s_barrier" ::: "memory");

  // facc *= ascale[row]
#pragma unroll
  for (int m = 0; m < 8; ++m) {
    f32x4 as_ = *(const f32x4*)(smem + ASL + (wr * 128 + m * 16 + l4 * 4) * 4);
#pragma unroll
    for (int n = 0; n < 4; ++n)
#pragma unroll
      for (int q = 0; q < 4; ++q) facc[m][n][q] *= as_[q];
  }

  // lora: facc = mfma_bf16(tr, lu, facc) -- ONE K=32 chunk (RANK == MFMA K)
  {
    bf16x8 aT[8], bL[4];
#pragma unroll
    for (int m = 0; m < 8; ++m)
      aT[m] = *(const bf16x8*)(smem + (wr * 128 + m * 16 + l15) * 64 + l4 * 16);
#pragma unroll
    for (int n = 0; n < 4; ++n)
      bL[n] = *(const bf16x8*)(smem + 16384 + (wc * 64 + n * 16 + l15) * 64 + l4 * 16);
#pragma unroll
    for (int m = 0; m < 8; ++m)
#pragma unroll
      for (int n = 0; n < 4; ++n)
        facc[m][n] = __builtin_amdgcn_mfma_f32_16x16x32_bf16(aT[m], bL[n], facc[m][n], 0, 0, 0);
  }

  // bias + store
#pragma unroll
  for (int m = 0; m < 8; ++m) {
    int rowb = tm + wr * 128 + m * 16 + l4 * 4;
#pragma unroll
    for (int n = 0; n < 4; ++n) {
      int col = tn + wc * 64 + n * 16 + l15;
      float bv = bias[col];
#pragma unroll
      for (int q = 0; q < 4; ++q)
        out[(size_t)(rowb + q) * OUT_F + col] = facc[m][n][q] + bv;
    }
  }
}

extern "C" void kernel_launch(void* const* d_in, const int* in_sizes, int n_in,
                              void* d_out, int out_size, void* d_ws, size_t ws_size,
                              hipStream_t stream) {
  const float* x = (const float*)d_in[0];
  const int* qw = (const int*)d_in[1];
  const float* wscale = (const float*)d_in[2];
  const float* ld = (const float*)d_in[3];
  const float* lu = (const float*)d_in[4];
  const float* bias = (const float*)d_in[5];
  float* out = (float*)d_out;

  char* ws = (char*)d_ws;
  char* A8 = ws;                                   // 16 MB
  char* B8 = ws + 16777216;                        // 16 MB
  float* wst = (float*)(ws + 33554432);            // 1 MB
  float* ascale = (float*)(ws + 34603008);         // 16 KB
  float* tr8 = (float*)(ws + 34619392);            // 4 MB
  u16* trb = (u16*)(ws + 38813696);                // 256 KB
  u16* lub = (u16*)(ws + 39075840);                // 256 KB

  prep_kernel<<<NTOK, 256, 0, stream>>>(x, A8, ascale);
  dequant_kernel<<<OUT_F, 256, 0, stream>>>(qw, lu, B8, lub);
  wtr_kernel<<<1024, 256, 0, stream>>>(wscale, wst);
  lorad_kernel<<<256, 256, 0, stream>>>(x, ld, tr8);
  trwrite_kernel<<<NTOK * RANK / 256, 256, 0, stream>>>(tr8, trb);
  gemm_kernel<<<(NTOK / 256) * (OUT_F / 256), 512, 0, stream>>>(A8, B8, wst, ascale,
                                                                trb, lub, bias, out);
}

// Round 12
// 521.103 us; speedup vs baseline: 1.0048x; 1.0048x over previous
//
#include <hip/hip_runtime.h>

typedef __bf16 bf16x8 __attribute__((ext_vector_type(8)));
typedef float f32x4 __attribute__((ext_vector_type(4)));
typedef int i32x4 __attribute__((ext_vector_type(4)));
typedef unsigned short u16;

#define IN_F 4096
#define OUT_F 4096
#define NTOK 4096
#define RANK 32

// LDS map (bytes)
#define D0A 0
#define D0B 16384
#define D1A 32768
#define D1B 49152
#define WSL 65536      /* wscale_t slab 64KB: [64][256] f32 */
#define ASL 131072     /* ascale slab 1KB */
#define LDS_TOT 132096

// round-to-nearest-even f32 -> bf16
__device__ __forceinline__ u16 f2bf(float f) {
  union { float f; unsigned u; } c; c.f = f;
  unsigned u = c.u;
  return (u16)((u + 0x7FFFu + ((u >> 16) & 1u)) >> 16);
}

__device__ __forceinline__ void gload_lds16(const void* g, void* l) {
  __builtin_amdgcn_global_load_lds((const __attribute__((address_space(1))) void*)g,
                                   (__attribute__((address_space(3))) void*)l,
                                   16, 0, 0);
}
__device__ __forceinline__ void gload_lds4(const void* g, void* l) {
  __builtin_amdgcn_global_load_lds((const __attribute__((address_space(1))) void*)g,
                                   (__attribute__((address_space(3))) void*)l,
                                   4, 0, 0);
}

// ---------------- prep: per-token amax -> ascale, int8 codes ----------------
__global__ __launch_bounds__(256) void prep_kernel(const float* __restrict__ x,
                                                   char* __restrict__ A8,
                                                   float* __restrict__ ascale) {
  int t = blockIdx.x;
  int tid = threadIdx.x;
  const float4* xr = (const float4*)(x + (size_t)t * IN_F);
  float4 v[4];
  float m = 0.f;
#pragma unroll
  for (int i = 0; i < 4; ++i) {
    v[i] = xr[tid + i * 256];
    m = fmaxf(m, fmaxf(fmaxf(fabsf(v[i].x), fabsf(v[i].y)),
                       fmaxf(fabsf(v[i].z), fabsf(v[i].w))));
  }
#pragma unroll
  for (int off = 32; off > 0; off >>= 1) m = fmaxf(m, __shfl_xor(m, off));
  __shared__ float wmax[4];
  if ((tid & 63) == 0) wmax[tid >> 6] = m;
  __syncthreads();
  m = fmaxf(fmaxf(wmax[0], wmax[1]), fmaxf(wmax[2], wmax[3]));
  float as = fmaxf(m, 1e-6f) / 7.f;
  float inv = 1.f / as;
  if (tid == 0) ascale[t] = as;
  char* Ar = A8 + (size_t)t * IN_F;
#pragma unroll
  for (int i = 0; i < 4; ++i) {
    float q0 = fminf(fmaxf(rintf(v[i].x * inv), -8.f), 7.f);
    float q1 = fminf(fmaxf(rintf(v[i].y * inv), -8.f), 7.f);
    float q2 = fminf(fmaxf(rintf(v[i].z * inv), -8.f), 7.f);
    float q3 = fminf(fmaxf(rintf(v[i].w * inv), -8.f), 7.f);
    char4 c;
    c.x = (char)(int)q0; c.y = (char)(int)q1; c.z = (char)(int)q2; c.w = (char)(int)q3;
    *(char4*)(Ar + (size_t)(tid + i * 256) * 4) = c;
  }
}

// ---------------- dequant: int4 codes -> int8 (no scaling), lu -> bf16 ----------------
__global__ __launch_bounds__(256) void dequant_kernel(const int* __restrict__ qw,
                                                      const float* __restrict__ lu,
                                                      char* __restrict__ B8,
                                                      u16* __restrict__ lub) {
  int o = blockIdx.x;
  int tid = threadIdx.x;
  const int4* qr = (const int4*)(qw + (size_t)o * IN_F);
  char* Br = B8 + (size_t)o * IN_F;
#pragma unroll
  for (int s = 0; s < 4; ++s) {
    int e = tid + s * 256;
    int4 q = qr[e];
    char4 c;
    c.x = (char)q.x; c.y = (char)q.y; c.z = (char)q.z; c.w = (char)q.w;
    *(char4*)(Br + (size_t)4 * e) = c;
  }
  if (tid < RANK) lub[(size_t)o * RANK + tid] = f2bf(lu[(size_t)o * RANK + tid]);
}

// ---------------- wtr: wscale[4096][64] -> wscale_t[64][4096] ----------------
__global__ __launch_bounds__(256) void wtr_kernel(const float* __restrict__ wscale,
                                                  float* __restrict__ wst) {
  int idx = blockIdx.x * 256 + threadIdx.x;   // 262144
  float v = wscale[idx];
  wst[(size_t)(idx & 63) * OUT_F + (idx >> 6)] = v;
}

// ---------------- lorad: tr = x @ ld^T, split-K=8 partials ----------------
__global__ __launch_bounds__(256) void lorad_kernel(const float* __restrict__ x,
                                                    const float* __restrict__ ld,
                                                    float* __restrict__ tr8) {
  __shared__ float Xs[128][68];
  __shared__ float Ls[32][68];
  int b = blockIdx.x;
  int t0 = (b >> 3) * 128;
  int kbase = (b & 7) * 512;
  int tid = threadIdx.x;
  int rb = tid & 7;
  int tb = tid >> 3;
  float acc[4][4];
#pragma unroll
  for (int i = 0; i < 4; ++i)
#pragma unroll
    for (int j = 0; j < 4; ++j) acc[i][j] = 0.f;

  for (int kc = 0; kc < 512; kc += 64) {
    int k0 = kbase + kc;
    __syncthreads();
#pragma unroll
    for (int s = 0; s < 8; ++s) {
      int e = tid + s * 256;
      int row = e >> 4, c4 = (e & 15) * 4;
      float4 vv = *(const float4*)(x + (size_t)(t0 + row) * IN_F + k0 + c4);
      *(float4*)&Xs[row][c4] = vv;
    }
#pragma unroll
    for (int s = 0; s < 2; ++s) {
      int e = tid + s * 256;
      int row = e >> 4, c4 = (e & 15) * 4;
      float4 vv = *(const float4*)(ld + (size_t)row * IN_F + k0 + c4);
      *(float4*)&Ls[row][c4] = vv;
    }
    __syncthreads();
    for (int k4 = 0; k4 < 64; k4 += 4) {
      float4 lv[4], xv[4];
#pragma unroll
      for (int r = 0; r < 4; ++r) lv[r] = *(float4*)&Ls[rb + r * 8][k4];
#pragma unroll
      for (int mm = 0; mm < 4; ++mm) xv[mm] = *(float4*)&Xs[tb + mm * 32][k4];
#pragma unroll
      for (int mm = 0; mm < 4; ++mm)
#pragma unroll
        for (int r = 0; r < 4; ++r)
          acc[mm][r] += xv[mm].x * lv[r].x + xv[mm].y * lv[r].y +
                        xv[mm].z * lv[r].z + xv[mm].w * lv[r].w;
    }
  }
  float* dst = tr8 + (size_t)(b & 7) * NTOK * RANK;
#pragma unroll
  for (int mm = 0; mm < 4; ++mm)
#pragma unroll
    for (int r = 0; r < 4; ++r)
      dst[(size_t)(t0 + tb + mm * 32) * RANK + rb + r * 8] = acc[mm][r];
}

// ---------------- trwrite: sum partials -> tr bf16 (no ascale) ----------------
__global__ __launch_bounds__(256) void trwrite_kernel(const float* __restrict__ tr8,
                                                      u16* __restrict__ trb) {
  int idx = blockIdx.x * 256 + threadIdx.x;
  float s = 0.f;
#pragma unroll
  for (int k = 0; k < 8; ++k) s += tr8[(size_t)k * NTOK * RANK + idx];
  trb[idx] = f2bf(s);
}

// ---------------- main GEMM: 256x256, i8 16x16x64, per-group wscale rescale ----------------
// ONE change vs r11: __launch_bounds__(512, 1). r11's (512,2) forced a
// 128-VGPR cap (4 waves/SIMD); this kernel needs ~210 (facc[8][4]=128 must be
// VGPRs -- VALU rescale touches them) -> allocator spilled accumulators ->
// 1.05 GB scratch write + read traffic per dispatch (measured WRITE_SIZE
// 1.12e9, MfmaUtil 6%). At (512,1): 2 waves/SIMD, 256 VGPR cap, no spill;
// 1 block/CU. In-block overlap (read-ahead + 256 VALU rescale ops/tile/wave
// against the MFMA pipe) substitutes for the lost cross-block overlap.
// Everything else identical to r11 (ledger, slots, vmcnt, epilogue).

#define PH_SYNC() do { __builtin_amdgcn_sched_barrier(0); \
                       asm volatile("s_barrier" ::: "memory"); \
                       asm volatile("s_waitcnt lgkmcnt(0)" ::: "memory"); \
                       __builtin_amdgcn_sched_barrier(0); } while (0)
#define PH_END() do { __builtin_amdgcn_sched_barrier(0); \
                      asm volatile("s_barrier" ::: "memory"); } while (0)
#define SB() __builtin_amdgcn_sched_barrier(0)

// stage one 128-row half (8KB) of A or B for K-tile at byte offset kb
#define STG_A(dst, H, kb) gload_lds16(ag + (size_t)(H) * (128 * 4096) + (kb), \
                                      smem + (dst) + (H) * 8192 + tid * 16)
#define STG_B(dst, H, kb) gload_lds16(bg + (size_t)(H) * (128 * 4096) + (kb), \
                                      smem + (dst) + (H) * 8192 + tid * 16)

// A-frag: 4 m-blocks, one b128 each (16 K-bytes): row = wr*128 + h*64 + m*16 + l15
#define READ_A8(dst, dbase, h) \
  _Pragma("unroll") for (int m2_ = 0; m2_ < 4; ++m2_) \
    dst[m2_] = *(const i32x4*)(smem + (dbase) + (h) * 4096 + m2_ * 1024 + aoff8);

// B-frag: 2 n-blocks starting at nq: row = wc*64 + n*16 + l15
#define READ_B8(dst, dbase, nq) \
  _Pragma("unroll") for (int j_ = 0; j_ < 2; ++j_) \
    dst[j_] = *(const i32x4*)(smem + (dbase) + 16384 + ((nq) + j_) * 1024 + boff8);

// quadrant: 4 m x 2 n, one K=64 MFMA each + per-group rescale
#define MFMAQ8(aS, bU, mb, nq, w0, w1) do { \
  __builtin_amdgcn_s_setprio(1); \
  _Pragma("unroll") for (int m2_ = 0; m2_ < 4; ++m2_) { \
    i32x4 ia0 = __builtin_amdgcn_mfma_i32_16x16x64_i8(aS[0 + m2_], bU[0], zero4, 0, 0, 0); \
    i32x4 ia1 = __builtin_amdgcn_mfma_i32_16x16x64_i8(aS[0 + m2_], bU[1], zero4, 0, 0, 0); \
    _Pragma("unroll") for (int e_ = 0; e_ < 4; ++e_) { \
      facc[(mb) + m2_][(nq)][e_]     += (w0) * (float)ia0[e_]; \
      facc[(mb) + m2_][(nq) + 1][e_] += (w1) * (float)ia1[e_]; \
    } \
  } \
  __builtin_amdgcn_s_setprio(0); } while (0)

__global__ __launch_bounds__(512, 1) void gemm_kernel(const char* __restrict__ A8,
                                                      const char* __restrict__ B8,
                                                      const float* __restrict__ wst,
                                                      const float* __restrict__ ascale,
                                                      const u16* __restrict__ trb,
                                                      const u16* __restrict__ lub,
                                                      const float* __restrict__ bias,
                                                      float* __restrict__ out) {
  __shared__ __align__(16) char smem[LDS_TOT];
  int b = blockIdx.x;
  int swz = (b & 7) * 32 + (b >> 3);     // 256 blocks, 8 XCDs -> bijective
  int by = swz >> 4, bx = swz & 15;
  int tm = by * 256, tn = bx * 256;
  int tid = threadIdx.x;
  int lane = tid & 63, wid = tid >> 6;
  int wr = wid >> 2, wc = wid & 3;       // 2x4 wave grid; wave owns 128x64 of C
  int l15 = lane & 15, l4 = lane >> 4;
  int aoff8 = wr * 8192 + l15 * 64 + l4 * 16;
  int boff8 = wc * 4096 + l15 * 64 + l4 * 16;
  int wcol = WSL + (wc * 64 + l15) * 4;  // + g*1024 + nblock*64

  // staging bases: thread covers row (tid>>2), chunk (tid&3)*16 within 64B rows
  const char* ag = A8 + (size_t)(tm + (tid >> 2)) * 4096 + (tid & 3) * 16;
  const char* bg = B8 + (size_t)(tn + (tid >> 2)) * 4096 + (tid & 3) * 16;

  const i32x4 zero4 = {0, 0, 0, 0};
  f32x4 facc[8][4];
#pragma unroll
  for (int i = 0; i < 8; ++i)
#pragma unroll
    for (int j = 0; j < 4; ++j) facc[i][j] = (f32x4){0.f, 0.f, 0.f, 0.f};

  // prologue: wscale slab (8), ascale (1, waves 0-3), tile0 full (4), tile1 {B.H0,B.H1,A.H0} (3)
#pragma unroll
  for (int h = 0; h < 8; ++h)
    gload_lds16(wst + (size_t)(h * 8 + (tid >> 6)) * OUT_F + tn + (tid & 63) * 4,
                smem + WSL + h * 8192 + tid * 16);
  if (tid < 256)
    gload_lds4(ascale + tm + tid, smem + ASL + tid * 4);
  STG_A(D0A, 0, 0);  STG_A(D0A, 1, 0);
  STG_B(D0B, 0, 0);  STG_B(D0B, 1, 0);
  STG_B(D1B, 0, 64); STG_B(D1B, 1, 64);
  STG_A(D1A, 0, 64);
  asm volatile("s_waitcnt vmcnt(3)" ::: "memory");  // wscale/ascale/tile0 landed
  PH_END();

  i32x4 aS0[4], aS1[4], bU0[2], bU1[2];
  READ_A8(aS0, D0A, 0);   // A(T0) h0; drained by P1's lgkm0

  for (int u = 0; u < 32; ++u) {
    int kb0 = u * 128;            // T0 = 2u at byte kb0; T1 at +64; T2 +128; T3 +192
    bool lastu = (u == 31);
    float w0, w1, w2, w3;

    // ---- P1: stage Ad1.H1(2u+1); pre B(T0)n01 | slot B(T0)n23 | Q(A0,B01) ----
    STG_A(D1A, 1, kb0 + 64);
    READ_B8(bU0, D0A, 0);
    PH_SYNC();
    w0 = *(const float*)(smem + wcol + (2 * u) * 1024);
    w1 = *(const float*)(smem + wcol + (2 * u) * 1024 + 64);
    READ_B8(bU1, D0A, 2);
    SB();
    MFMAQ8(aS0, bU0, 0, 0, w0, w1);

    // ---- P2: slot A(T0)h1 | Q(A0,B23) ----
    PH_SYNC();
    w2 = *(const float*)(smem + wcol + (2 * u) * 1024 + 128);
    w3 = *(const float*)(smem + wcol + (2 * u) * 1024 + 192);
    READ_A8(aS1, D0A, 1);
    SB();
    MFMAQ8(aS0, bU1, 0, 2, w2, w3);
    PH_END();

    // ---- P3: stage Bd0 both halves (2u+2) | Q(A1,B23) ----
    if (!lastu) { STG_B(D0B, 0, kb0 + 128); STG_B(D0B, 1, kb0 + 128); }
    PH_SYNC();
    MFMAQ8(aS1, bU1, 4, 2, w2, w3);
    PH_END();

    // ---- P4: stage Ad0 both halves (2u+2); counted vmcnt | slot A(T1)h0 | Q(A1,B01) ----
    if (!lastu) {
      STG_A(D0A, 0, kb0 + 128); STG_A(D0A, 1, kb0 + 128);
      asm volatile("s_waitcnt vmcnt(4)" ::: "memory");  // forces P7',P8',P1 -> dbuf1 ready
    } else {
      asm volatile("s_waitcnt vmcnt(0)" ::: "memory");
    }
    PH_SYNC();
    READ_A8(aS0, D1A, 0);
    SB();
    MFMAQ8(aS1, bU0, 4, 0, w0, w1);

    // ---- P5: pre B(T1)n01 | slot B(T1)n23 | Q(A0,B01) ----
    READ_B8(bU0, D1A, 0);
    PH_SYNC();
    w0 = *(const float*)(smem + wcol + (2 * u + 1) * 1024);
    w1 = *(const float*)(smem + wcol + (2 * u + 1) * 1024 + 64);
    READ_B8(bU1, D1A, 2);
    SB();
    MFMAQ8(aS0, bU0, 0, 0, w0, w1);

    // ---- P6: slot A(T1)h1 | Q(A0,B23) ----
    PH_SYNC();
    w2 = *(const float*)(smem + wcol + (2 * u + 1) * 1024 + 128);
    w3 = *(const float*)(smem + wcol + (2 * u + 1) * 1024 + 192);
    READ_A8(aS1, D1A, 1);
    SB();
    MFMAQ8(aS0, bU1, 0, 2, w2, w3);
    PH_END();

    // ---- P7: stage Bd1.H0 (2u+3) | Q(A1,B23) ----
    if (!lastu) STG_B(D1B, 0, kb0 + 192);
    PH_SYNC();
    MFMAQ8(aS1, bU1, 4, 2, w2, w3);
    PH_END();

    // ---- P8: stage Bd1.H1 + Ad1.H0 (2u+3); counted vmcnt | slot A(T0')h0 | Q(A1,B01) ----
    if (!lastu) {
      STG_B(D1B, 1, kb0 + 192);
      STG_A(D1A, 0, kb0 + 192);
      asm volatile("s_waitcnt vmcnt(3)" ::: "memory");  // forces P3,P4 -> dbuf0 ready
    }
    PH_SYNC();
    if (!lastu) { READ_A8(aS0, D0A, 0); }
    SB();
    MFMAQ8(aS1, bU0, 4, 0, w0, w1);
    PH_END();
  }

  // ---- epilogue: stage tr/lu into dbuf space ----
  {
    const char* trg = (const char*)trb + (size_t)(tm + (tid >> 2)) * 64 + (tid & 3) * 16;
    gload_lds16(trg, smem + tid * 16);
    gload_lds16(trg + (size_t)128 * 64, smem + 8192 + tid * 16);
    const char* lug = (const char*)lub + (size_t)(tn + (tid >> 2)) * 64 + (tid & 3) * 16;
    gload_lds16(lug, smem + 16384 + tid * 16);
    gload_lds16(lug + (size_t)128 * 64, smem + 16384 + 8192 + tid * 16);
  }
  asm volatile("s_waitcnt vmcnt(0)" ::: "memory");
  asm volatile("s_barrier" ::: "memory");

  // facc *= ascale[row]
#pragma unroll
  for (int m = 0; m < 8; ++m) {
    f32x4 as_ = *(const f32x4*)(smem + ASL + (wr * 128 + m * 16 + l4 * 4) * 4);
#pragma unroll
    for (int n = 0; n < 4; ++n)
#pragma unroll
      for (int q = 0; q < 4; ++q) facc[m][n][q] *= as_[q];
  }

  // lora: facc = mfma_bf16(tr, lu, facc) -- ONE K=32 chunk (RANK == MFMA K)
  {
    bf16x8 aT[8], bL[4];
#pragma unroll
    for (int m = 0; m < 8; ++m)
      aT[m] = *(const bf16x8*)(smem + (wr * 128 + m * 16 + l15) * 64 + l4 * 16);
#pragma unroll
    for (int n = 0; n < 4; ++n)
      bL[n] = *(const bf16x8*)(smem + 16384 + (wc * 64 + n * 16 + l15) * 64 + l4 * 16);
#pragma unroll
    for (int m = 0; m < 8; ++m)
#pragma unroll
      for (int n = 0; n < 4; ++n)
        facc[m][n] = __builtin_amdgcn_mfma_f32_16x16x32_bf16(aT[m], bL[n], facc[m][n], 0, 0, 0);
  }

  // bias + store
#pragma unroll
  for (int m = 0; m < 8; ++m) {
    int rowb = tm + wr * 128 + m * 16 + l4 * 4;
#pragma unroll
    for (int n = 0; n < 4; ++n) {
      int col = tn + wc * 64 + n * 16 + l15;
      float bv = bias[col];
#pragma unroll
      for (int q = 0; q < 4; ++q)
        out[(size_t)(rowb + q) * OUT_F + col] = facc[m][n][q] + bv;
    }
  }
}

extern "C" void kernel_launch(void* const* d_in, const int* in_sizes, int n_in,
                              void* d_out, int out_size, void* d_ws, size_t ws_size,
                              hipStream_t stream) {
  const float* x = (const float*)d_in[0];
  const int* qw = (const int*)d_in[1];
  const float* wscale = (const float*)d_in[2];
  const float* ld = (const float*)d_in[3];
  const float* lu = (const float*)d_in[4];
  const float* bias = (const float*)d_in[5];
  float* out = (float*)d_out;

  char* ws = (char*)d_ws;
  char* A8 = ws;                                   // 16 MB
  char* B8 = ws + 16777216;                        // 16 MB
  float* wst = (float*)(ws + 33554432);            // 1 MB
  float* ascale = (float*)(ws + 34603008);         // 16 KB
  float* tr8 = (float*)(ws + 34619392);            // 4 MB
  u16* trb = (u16*)(ws + 38813696);                // 256 KB
  u16* lub = (u16*)(ws + 39075840);                // 256 KB

  prep_kernel<<<NTOK, 256, 0, stream>>>(x, A8, ascale);
  dequant_kernel<<<OUT_F, 256, 0, stream>>>(qw, lu, B8, lub);
  wtr_kernel<<<1024, 256, 0, stream>>>(wscale, wst);
  lorad_kernel<<<256, 256, 0, stream>>>(x, ld, tr8);
  trwrite_kernel<<<NTOK * RANK / 256, 256, 0, stream>>>(tr8, trb);
  gemm_kernel<<<(NTOK / 256) * (OUT_F / 256), 512, 0, stream>>>(A8, B8, wst, ascale,
                                                                trb, lub, bias, out);
}